// Round 2
// baseline (17999.928 us; speedup 1.0000x reference)
//
#include <hip/hip_runtime.h>
#include <math.h>

// ---------------------------------------------------------------------------
// LocalSlidingWindow_DisentangledAttention  (B=4, S=8192, H=768, NH=12, HD=64,
// BS=128, BUCKETS=256)  — Round 2: fp32 baseline, ws-size-adaptive chunking.
//
// Round-1 abort diagnosis: 412 MB workspace layout likely exceeded ws_size ->
// OOB writes -> device abort. Now we chunk the batch dimension (nb in {4,2,1})
// so the footprint is nb*102.2MB + 3.1MB and pick the largest nb that fits.
//
// Pipeline (per chunk of nb batches):
//   pos_gemm   (once): [512,768] x [768,1536] -> posq, posk  [h,512,64]
//   zero_halo  (once): zero the 128-row halo blocks of padded k/v
//   qkv_gemm   : [nb*8192,768] x [768,2304] -> q [bh,s,d], k/v padded [bh,sp,d]
//   attn_kernel: per (b,blk,head,32-q-rows): c2c+c2p+p2c, softmax(384), PV
//   out_gemm   : ctx @ Wo + bo + hidden -> d_out rows of this chunk
//   ln_kernel  (once): in-place LayerNorm on d_out
// ---------------------------------------------------------------------------

#define NHEADS 12
#define HDIM   64
#define SEQ    8192
#define SPAD   8448          // SEQ + 2*BS halo
#define HID    768
#define BSZ    128
#define WIN    384
#define PBUCK  512

#define Q_B    6291456       // 12*8192*64  floats per batch
#define KV_B   6488064       // 12*8448*64
#define CTX_B  6291456       // 8192*768
#define POS_E  393216        // 12*512*64

// idx(rel) for rel in [-383, 127]; replicates make_log_bucket_position + clip.
__device__ __forceinline__ int bucket_idx(int rel) {
  if (rel >= -128) {
    return rel + 256;                       // identity region -> [128, 383]
  }
  float a = (float)(-rel);                  // 129..383
  float t = logf(a * (1.0f / 128.0f));
  t = t / 0.6892332813f;                    // float32(log(255/128))
  t = t * 127.0f;
  int lp = (int)(ceilf(t) + 128.0f);        // log_pos
  int r = 256 - lp;                         // (-log_pos) + 256, clip low to 0
  return r < 0 ? 0 : r;
}

__global__ __launch_bounds__(256) void zero_halo(float* __restrict__ kws,
                                                 float* __restrict__ vws) {
  int t = blockIdx.x * blockDim.x + threadIdx.x;   // nb*12*256*64 threads
  int d = t & 63;
  int r = (t >> 6) & 255;
  int bh = t >> 14;
  int row = (r < 128) ? r : (SPAD - 256 + r);       // 0..127 or 8320..8447
  size_t off = ((size_t)bh * SPAD + row) * HDIM + d;
  kws[off] = 0.f;
  vws[off] = 0.f;
}

// Positional projection: [512,768] x [768, 1536 (q|k)] -> posq, posk.
__global__ __launch_bounds__(256) void pos_gemm(
    const float* __restrict__ relpos, const float* __restrict__ Wq,
    const float* __restrict__ Wk, const float* __restrict__ bq,
    const float* __restrict__ bk, float* __restrict__ posq,
    float* __restrict__ posk) {
  __shared__ float At[32][68];
  __shared__ float Bs[32][68];
  int m0 = blockIdx.x * 64;
  int n0 = blockIdx.y * 64;                 // [0,1536)
  int w = n0 / HID;                         // 0:q 1:k
  int nc0 = n0 % HID;
  const float* W = (w == 0) ? Wq : Wk;
  const float* bias = (w == 0) ? bq : bk;
  int t = threadIdx.x;
  int tx = t & 15, ty = t >> 4;
  float acc[4][4] = {};
  for (int k0 = 0; k0 < HID; k0 += 32) {
#pragma unroll
    for (int u = 0; u < 2; ++u) {
      int f = t * 2 + u;
      int r = f >> 3, c4 = f & 7;
      float4 av = *(const float4*)(relpos + (size_t)(m0 + r) * HID + k0 + c4 * 4);
      At[c4 * 4 + 0][r] = av.x;
      At[c4 * 4 + 1][r] = av.y;
      At[c4 * 4 + 2][r] = av.z;
      At[c4 * 4 + 3][r] = av.w;
    }
#pragma unroll
    for (int u = 0; u < 2; ++u) {
      int f = t * 2 + u;
      int kk = f >> 4, c4 = f & 15;
      float4 bv4 = *(const float4*)(W + (size_t)(k0 + kk) * HID + nc0 + c4 * 4);
      *(float4*)&Bs[kk][c4 * 4] = bv4;
    }
    __syncthreads();
#pragma unroll
    for (int kk = 0; kk < 32; ++kk) {
      float4 a4 = *(const float4*)&At[kk][ty * 4];
      float4 b4 = *(const float4*)&Bs[kk][tx * 4];
      float av[4] = {a4.x, a4.y, a4.z, a4.w};
      float bvv[4] = {b4.x, b4.y, b4.z, b4.w};
#pragma unroll
      for (int i = 0; i < 4; ++i)
#pragma unroll
        for (int jj = 0; jj < 4; ++jj) acc[i][jj] += av[i] * bvv[jj];
    }
    __syncthreads();
  }
#pragma unroll
  for (int i = 0; i < 4; ++i) {
    int p = m0 + ty * 4 + i;                // bucket row
#pragma unroll
    for (int jj = 0; jj < 4; ++jj) {
      int nc = nc0 + tx * 4 + jj;
      int h = nc >> 6, d = nc & 63;
      float val = acc[i][jj] + bias[nc];
      if (w == 0)
        posq[((size_t)h * PBUCK + p) * HDIM + d] = val;
      else
        posk[((size_t)h * PBUCK + p) * HDIM + d] = val;
    }
  }
}

// Fused QKV projection for nrows = nb*8192 hidden rows.
__global__ __launch_bounds__(256) void qkv_gemm(
    const float* __restrict__ hidden, const float* __restrict__ Wq,
    const float* __restrict__ Wk, const float* __restrict__ Wv,
    const float* __restrict__ bq, const float* __restrict__ bk,
    const float* __restrict__ bv, float* __restrict__ qws,
    float* __restrict__ kws, float* __restrict__ vws) {
  __shared__ float At[32][68];
  __shared__ float Bs[32][68];
  int m0 = blockIdx.x * 64;
  int n0 = blockIdx.y * 64;                 // [0,2304)
  int w = n0 / HID;                         // 0:q 1:k 2:v (uniform per block)
  int nc0 = n0 % HID;
  const float* W = (w == 0) ? Wq : (w == 1 ? Wk : Wv);
  const float* bias = (w == 0) ? bq : (w == 1 ? bk : bv);
  int t = threadIdx.x;
  int tx = t & 15, ty = t >> 4;
  float acc[4][4] = {};
  for (int k0 = 0; k0 < HID; k0 += 32) {
#pragma unroll
    for (int u = 0; u < 2; ++u) {
      int f = t * 2 + u;
      int r = f >> 3, c4 = f & 7;
      float4 av = *(const float4*)(hidden + (size_t)(m0 + r) * HID + k0 + c4 * 4);
      At[c4 * 4 + 0][r] = av.x;
      At[c4 * 4 + 1][r] = av.y;
      At[c4 * 4 + 2][r] = av.z;
      At[c4 * 4 + 3][r] = av.w;
    }
#pragma unroll
    for (int u = 0; u < 2; ++u) {
      int f = t * 2 + u;
      int kk = f >> 4, c4 = f & 15;
      float4 bv4 = *(const float4*)(W + (size_t)(k0 + kk) * HID + nc0 + c4 * 4);
      *(float4*)&Bs[kk][c4 * 4] = bv4;
    }
    __syncthreads();
#pragma unroll
    for (int kk = 0; kk < 32; ++kk) {
      float4 a4 = *(const float4*)&At[kk][ty * 4];
      float4 b4 = *(const float4*)&Bs[kk][tx * 4];
      float av[4] = {a4.x, a4.y, a4.z, a4.w};
      float bvv[4] = {b4.x, b4.y, b4.z, b4.w};
#pragma unroll
      for (int i = 0; i < 4; ++i)
#pragma unroll
        for (int jj = 0; jj < 4; ++jj) acc[i][jj] += av[i] * bvv[jj];
    }
    __syncthreads();
  }
#pragma unroll
  for (int i = 0; i < 4; ++i) {
    int gm = m0 + ty * 4 + i;
    int bl = gm >> 13, s = gm & 8191;       // batch-local, token
#pragma unroll
    for (int jj = 0; jj < 4; ++jj) {
      int nc = nc0 + tx * 4 + jj;
      int h = nc >> 6, d = nc & 63;
      float val = acc[i][jj] + bias[nc];
      if (w == 0)
        qws[(((size_t)bl * NHEADS + h) * SEQ + s) * HDIM + d] = val;
      else if (w == 1)
        kws[(((size_t)bl * NHEADS + h) * SPAD + s + BSZ) * HDIM + d] = val;
      else
        vws[(((size_t)bl * NHEADS + h) * SPAD + s + BSZ) * HDIM + d] = val;
    }
  }
}

// Attention: one block = (bl, n, h, qt). 32 q rows x 384 window keys.
// thread t: j = t&7 (k slice, k = i*8+j), qq = t>>3 (q row).
__global__ __launch_bounds__(256) void attn_kernel(
    const float* __restrict__ qws, const float* __restrict__ kws,
    const float* __restrict__ vws, const float* __restrict__ posq,
    const float* __restrict__ posk, float* __restrict__ ctx) {
  __shared__ float sc[48 * 256];
  int t = threadIdx.x;
  int j = t & 7, qq = t >> 3;
  int bid = blockIdx.x;
  int qt = bid & 3;
  int tmp = bid >> 2;
  int h = tmp % NHEADS;
  tmp /= NHEADS;
  int n = tmp & 63;
  int bl = tmp >> 6;

  int qpos = qt * 32 + qq;           // 0..127
  int s = n * BSZ + qpos;
  const float4* qrow =
      (const float4*)(qws + (((size_t)bl * NHEADS + h) * SEQ + s) * HDIM);
  float4 q4[16];
#pragma unroll
  for (int d = 0; d < 16; ++d) q4[d] = qrow[d];

  const float* kbase = kws + (((size_t)bl * NHEADS + h) * SPAD + n * BSZ) * HDIM;
  const float* pkh = posk + (size_t)h * PBUCK * HDIM;
  const float* pqh = posq + (size_t)h * PBUCK * HDIM;

  for (int i = 0; i < 48; ++i) {
    int kwin = i * 8 + j;            // 0..383
    const float4* kr = (const float4*)(kbase + (size_t)kwin * HDIM);
    int idx = bucket_idx(qpos - kwin);
    const float4* pkr = (const float4*)(pkh + (size_t)idx * HDIM);
    const float4* pqr = (const float4*)(pqh + (size_t)idx * HDIM);
    float c2c = 0.f, c2p = 0.f, p2c = 0.f;
#pragma unroll
    for (int d = 0; d < 16; ++d) {
      float4 kv = kr[d];
      float4 pk = pkr[d];
      float4 pq = pqr[d];
      float4 qv = q4[d];
      c2c += qv.x * kv.x + qv.y * kv.y + qv.z * kv.z + qv.w * kv.w;
      c2p += qv.x * pk.x + qv.y * pk.y + qv.z * pk.z + qv.w * pk.w;
      p2c += kv.x * pq.x + kv.y * pq.y + kv.z * pq.z + kv.w * pq.w;
    }
    sc[i * 256 + t] = (c2c + c2p + p2c) * 0.07216878365f;   // 1/sqrt(192)
  }

  // softmax over 384 = 48 local x 8 lanes (lanes with same qq are consecutive)
  float m = -1e30f;
  for (int i = 0; i < 48; ++i) m = fmaxf(m, sc[i * 256 + t]);
#pragma unroll
  for (int o = 1; o < 8; o <<= 1) m = fmaxf(m, __shfl_xor(m, o));
  float l = 0.f;
  for (int i = 0; i < 48; ++i) {
    float p = expf(sc[i * 256 + t] - m);
    l += p;
    sc[i * 256 + t] = p;
  }
#pragma unroll
  for (int o = 1; o < 8; o <<= 1) l += __shfl_xor(l, o);
  float inv = 1.0f / l;

  // PV
  const float* vbase = vws + (((size_t)bl * NHEADS + h) * SPAD + n * BSZ) * HDIM;
  float4 acc[16];
#pragma unroll
  for (int d = 0; d < 16; ++d) acc[d] = make_float4(0.f, 0.f, 0.f, 0.f);
  for (int i = 0; i < 48; ++i) {
    float p = sc[i * 256 + t] * inv;
    const float4* vr = (const float4*)(vbase + (size_t)(i * 8 + j) * HDIM);
#pragma unroll
    for (int d = 0; d < 16; ++d) {
      float4 vv = vr[d];
      acc[d].x += p * vv.x;
      acc[d].y += p * vv.y;
      acc[d].z += p * vv.z;
      acc[d].w += p * vv.w;
    }
  }
#pragma unroll
  for (int d = 0; d < 16; ++d) {
#pragma unroll
    for (int o = 1; o < 8; o <<= 1) {
      acc[d].x += __shfl_xor(acc[d].x, o);
      acc[d].y += __shfl_xor(acc[d].y, o);
      acc[d].z += __shfl_xor(acc[d].z, o);
      acc[d].w += __shfl_xor(acc[d].w, o);
    }
  }
  // lane j stores float4 indices 2j, 2j+1  (ctx layout [bl,S,H], heads packed)
  float4* outp = (float4*)(ctx + ((size_t)bl * SEQ + s) * HID + h * HDIM);
#pragma unroll
  for (int d = 0; d < 16; ++d)
    if ((d >> 1) == j) outp[d] = acc[d];
}

// Out projection + residual: out = ctx @ Wo + bo + hidden (chunk rows).
__global__ __launch_bounds__(256) void out_gemm(
    const float* __restrict__ ctx, const float* __restrict__ Wo,
    const float* __restrict__ bo, const float* __restrict__ hidden,
    float* __restrict__ out) {
  __shared__ float At[32][68];
  __shared__ float Bs[32][68];
  int m0 = blockIdx.x * 64;
  int n0 = blockIdx.y * 64;
  int t = threadIdx.x;
  int tx = t & 15, ty = t >> 4;
  float acc[4][4] = {};
  for (int k0 = 0; k0 < HID; k0 += 32) {
#pragma unroll
    for (int u = 0; u < 2; ++u) {
      int f = t * 2 + u;
      int r = f >> 3, c4 = f & 7;
      float4 av = *(const float4*)(ctx + (size_t)(m0 + r) * HID + k0 + c4 * 4);
      At[c4 * 4 + 0][r] = av.x;
      At[c4 * 4 + 1][r] = av.y;
      At[c4 * 4 + 2][r] = av.z;
      At[c4 * 4 + 3][r] = av.w;
    }
#pragma unroll
    for (int u = 0; u < 2; ++u) {
      int f = t * 2 + u;
      int kk = f >> 4, c4 = f & 15;
      float4 bv4 = *(const float4*)(Wo + (size_t)(k0 + kk) * HID + n0 + c4 * 4);
      *(float4*)&Bs[kk][c4 * 4] = bv4;
    }
    __syncthreads();
#pragma unroll
    for (int kk = 0; kk < 32; ++kk) {
      float4 a4 = *(const float4*)&At[kk][ty * 4];
      float4 b4 = *(const float4*)&Bs[kk][tx * 4];
      float av[4] = {a4.x, a4.y, a4.z, a4.w};
      float bvv[4] = {b4.x, b4.y, b4.z, b4.w};
#pragma unroll
      for (int i = 0; i < 4; ++i)
#pragma unroll
        for (int jj = 0; jj < 4; ++jj) acc[i][jj] += av[i] * bvv[jj];
    }
    __syncthreads();
  }
#pragma unroll
  for (int i = 0; i < 4; ++i) {
    int gm = m0 + ty * 4 + i;
#pragma unroll
    for (int jj = 0; jj < 4; ++jj) {
      int nc = n0 + tx * 4 + jj;
      float val = acc[i][jj] + bo[nc] + hidden[(size_t)gm * HID + nc];
      out[(size_t)gm * HID + nc] = val;
    }
  }
}

// In-place LayerNorm over rows of 768.
__global__ __launch_bounds__(256) void ln_kernel(float* __restrict__ x,
                                                 const float* __restrict__ sc,
                                                 const float* __restrict__ bi) {
  __shared__ float red[8];
  int row = blockIdx.x;
  int t = threadIdx.x;
  float* xr = x + (size_t)row * HID;
  float e0 = xr[t], e1 = xr[t + 256], e2 = xr[t + 512];
  float ssum = e0 + e1 + e2;
#pragma unroll
  for (int o = 1; o < 64; o <<= 1) ssum += __shfl_xor(ssum, o);
  int w = t >> 6;
  if ((t & 63) == 0) red[w] = ssum;
  __syncthreads();
  float mu = (red[0] + red[1] + red[2] + red[3]) * (1.0f / 768.0f);
  float d0 = e0 - mu, d1 = e1 - mu, d2 = e2 - mu;
  float sq = d0 * d0 + d1 * d1 + d2 * d2;
#pragma unroll
  for (int o = 1; o < 64; o <<= 1) sq += __shfl_xor(sq, o);
  __syncthreads();
  if ((t & 63) == 0) red[4 + w] = sq;
  __syncthreads();
  float var = (red[4] + red[5] + red[6] + red[7]) * (1.0f / 768.0f);
  float rstd = 1.0f / sqrtf(var + 1e-7f);
  xr[t] = d0 * rstd * sc[t] + bi[t];
  xr[t + 256] = d1 * rstd * sc[t + 256] + bi[t + 256];
  xr[t + 512] = d2 * rstd * sc[t + 512] + bi[t + 512];
}

extern "C" void kernel_launch(void* const* d_in, const int* in_sizes, int n_in,
                              void* d_out, int out_size, void* d_ws,
                              size_t ws_size, hipStream_t stream) {
  (void)in_sizes; (void)n_in; (void)out_size;
  const float* hidden = (const float*)d_in[0];
  const float* relpos = (const float*)d_in[1];
  const float* Wq = (const float*)d_in[2];
  const float* bq = (const float*)d_in[3];
  const float* Wk = (const float*)d_in[4];
  const float* bk = (const float*)d_in[5];
  const float* Wv = (const float*)d_in[6];
  const float* bv = (const float*)d_in[7];
  const float* Wo = (const float*)d_in[8];
  const float* bo = (const float*)d_in[9];
  const float* lns = (const float*)d_in[10];
  const float* lnb = (const float*)d_in[11];
  float* out = (float*)d_out;

  // Pick largest batch-chunk nb in {4,2,1} whose layout fits ws_size.
  const size_t PER_B = (size_t)Q_B + 2 * (size_t)KV_B + (size_t)CTX_B;
  int nb = 4;
  while (nb > 1 &&
         ((size_t)nb * PER_B + 2 * (size_t)POS_E) * sizeof(float) > ws_size)
    nb >>= 1;

  float* ws = (float*)d_ws;
  float* qws = ws;
  float* kws = qws + (size_t)nb * Q_B;
  float* vws = kws + (size_t)nb * KV_B;
  float* ctx = vws + (size_t)nb * KV_B;
  float* posq = ctx + (size_t)nb * CTX_B;
  float* posk = posq + POS_E;

  pos_gemm<<<dim3(8, 24), 256, 0, stream>>>(relpos, Wq, Wk, bq, bk, posq, posk);
  zero_halo<<<nb * 768, 256, 0, stream>>>(kws, vws);

  for (int b0 = 0; b0 < 4; b0 += nb) {
    const float* hchunk = hidden + (size_t)b0 * SEQ * HID;
    qkv_gemm<<<dim3(nb * 128, 36), 256, 0, stream>>>(hchunk, Wq, Wk, Wv, bq,
                                                     bk, bv, qws, kws, vws);
    attn_kernel<<<nb * 3072, 256, 0, stream>>>(qws, kws, vws, posq, posk, ctx);
    out_gemm<<<dim3(nb * 128, 12), 256, 0, stream>>>(
        ctx, Wo, bo, hchunk, out + (size_t)b0 * SEQ * HID);
  }
  ln_kernel<<<32768, 256, 0, stream>>>(out, lns, lnb);
}

// Round 3
// 2559.862 us; speedup vs baseline: 7.0316x; 7.0316x over previous
//
#include <hip/hip_runtime.h>
#include <math.h>

// ---------------------------------------------------------------------------
// LocalSlidingWindow_DisentangledAttention — Round 3: MFMA bf16 attention.
// B=4, S=8192, H=768, NH=12, HD=64, BS=128, WIN=384, BUCKETS=256.
//
// qkv_gemm (fp32 math) -> bf16 q[bh,s,d], k[bh,spad,d], vT[bh,d,spad]
// pos_gemm -> bf16 posq/posk [h,512,64]
// attn_kernel: per (b,h,n) block, 8 waves, mfma_f32_16x16x32_bf16:
//   S_s[k][q] = c2c + c2p + p2c (swapped operands), softmax in-reg, PV.
// out_gemm: ctx(bf16) @ Wo + bo + hidden -> out ; ln_kernel in-place.
// ---------------------------------------------------------------------------

#define NHEADS 12
#define HDIM   64
#define SEQ    8192
#define SPAD   8448
#define HID    768
#define BSZ    128
#define WIN    384
#define PBUCK  512

typedef __attribute__((ext_vector_type(8))) short bf16x8;
typedef __attribute__((ext_vector_type(4))) float f32x4;
#define MFMA16(a, b, c) __builtin_amdgcn_mfma_f32_16x16x32_bf16((a), (b), (c), 0, 0, 0)

// LDS byte map (dynamic, 155136 total)
#define C2P_OFF 0        // [128][392] bf16 = 100352   (phase 1-2)
#define K_OFF   0        // [384][64]  bf16 = 49152    (phase 3+)
#define PQ_OFF  49152    // [384][64]  bf16 = 49152    (phase 3-4)
#define VT_OFF  49152    // [64][384]  bf16 = 49152    (PV phase)
#define T_OFF   100352   // [32][184]  bf16 = 11776
#define Q_OFF   112128   // [128][64]  bf16 = 16384
#define PKH_OFF 128512   // [192][64]  bf16 = 24576
#define LUT_OFF 153088   // [511] int  = 2044
#define SMEM_BYTES 155136

__device__ __forceinline__ unsigned short f2bf(float f) {
  unsigned int x = __builtin_bit_cast(unsigned int, f);
  unsigned int r = (x + 0x7FFFu + ((x >> 16) & 1u)) >> 16;
  return (unsigned short)r;
}
__device__ __forceinline__ float bf2f(unsigned short u) {
  unsigned int x = ((unsigned int)u) << 16;
  return __builtin_bit_cast(float, x);
}

// idx(rel) for rel in [-383, 127]
__device__ __forceinline__ int bucket_idx(int rel) {
  if (rel >= -128) return rel + 256;
  float a = (float)(-rel);
  float t = logf(a * (1.0f / 128.0f));
  t = t / 0.6892332813f;
  t = t * 127.0f;
  int lp = (int)(ceilf(t) + 128.0f);
  int r = 256 - lp;
  return r < 0 ? 0 : r;
}

// Fragment load from swizzled row-major bf16 LDS tile.
__device__ __forceinline__ bf16x8 ldfrag(const char* sm, int byteBase, int row,
                                         int rowBytes, int slice, int g) {
  const int swz = (row & 7) << 4;
  const char* p = sm + byteBase + row * rowBytes;
  union { bf16x8 v; uint2 u2[2]; } w;
  w.u2[0] = *(const uint2*)(p + (((slice << 6) + (g << 3)) ^ swz));
  w.u2[1] = *(const uint2*)(p + (((slice << 6) + 32 + (g << 3)) ^ swz));
  return w.v;
}

// ---------------------------------------------------------------------------
__global__ __launch_bounds__(256) void zero_halo(unsigned short* __restrict__ kws,
                                                 unsigned short* __restrict__ vt) {
  int t = blockIdx.x * blockDim.x + threadIdx.x;  // 786432
  int d = t & 63;
  int r = (t >> 6) & 255;
  int bh = t >> 14;
  int row = (r < 128) ? r : (SPAD - 256 + r);
  kws[((size_t)bh * SPAD + row) * HDIM + d] = 0;
  int rem = t & 16383;
  int d2 = rem >> 8;
  int c = rem & 255;
  int col = (c < 128) ? c : (SPAD - 256 + c);
  vt[(size_t)bh * (HDIM * SPAD) + (size_t)d2 * SPAD + col] = 0;
}

// Positional projection -> bf16 posq/posk [h][512][64]
__global__ __launch_bounds__(256) void pos_gemm(
    const float* __restrict__ relpos, const float* __restrict__ Wq,
    const float* __restrict__ Wk, const float* __restrict__ bq,
    const float* __restrict__ bk, unsigned short* __restrict__ posq,
    unsigned short* __restrict__ posk) {
  __shared__ float At[32][68];
  __shared__ float Bs[32][68];
  int m0 = blockIdx.x * 64;
  int n0 = blockIdx.y * 64;
  int w = n0 / HID;
  int nc0 = n0 % HID;
  const float* W = (w == 0) ? Wq : Wk;
  const float* bias = (w == 0) ? bq : bk;
  int t = threadIdx.x;
  int tx = t & 15, ty = t >> 4;
  float acc[4][4] = {};
  for (int k0 = 0; k0 < HID; k0 += 32) {
#pragma unroll
    for (int u = 0; u < 2; ++u) {
      int f = t * 2 + u;
      int r = f >> 3, c4 = f & 7;
      float4 av = *(const float4*)(relpos + (size_t)(m0 + r) * HID + k0 + c4 * 4);
      At[c4 * 4 + 0][r] = av.x; At[c4 * 4 + 1][r] = av.y;
      At[c4 * 4 + 2][r] = av.z; At[c4 * 4 + 3][r] = av.w;
    }
#pragma unroll
    for (int u = 0; u < 2; ++u) {
      int f = t * 2 + u;
      int kk = f >> 4, c4 = f & 15;
      float4 bv4 = *(const float4*)(W + (size_t)(k0 + kk) * HID + nc0 + c4 * 4);
      *(float4*)&Bs[kk][c4 * 4] = bv4;
    }
    __syncthreads();
#pragma unroll
    for (int kk = 0; kk < 32; ++kk) {
      float4 a4 = *(const float4*)&At[kk][ty * 4];
      float4 b4 = *(const float4*)&Bs[kk][tx * 4];
      float av[4] = {a4.x, a4.y, a4.z, a4.w};
      float bvv[4] = {b4.x, b4.y, b4.z, b4.w};
#pragma unroll
      for (int i = 0; i < 4; ++i)
#pragma unroll
        for (int jj = 0; jj < 4; ++jj) acc[i][jj] += av[i] * bvv[jj];
    }
    __syncthreads();
  }
  int h = nc0 >> 6;
  unsigned short* dst = (w == 0) ? posq : posk;
#pragma unroll
  for (int i = 0; i < 4; ++i) {
    int p = m0 + ty * 4 + i;
    ushort4 o;
    o.x = f2bf(acc[i][0] + bias[nc0 + tx * 4 + 0]);
    o.y = f2bf(acc[i][1] + bias[nc0 + tx * 4 + 1]);
    o.z = f2bf(acc[i][2] + bias[nc0 + tx * 4 + 2]);
    o.w = f2bf(acc[i][3] + bias[nc0 + tx * 4 + 3]);
    *(ushort4*)(dst + ((size_t)h * PBUCK + p) * HDIM + tx * 4) = o;
  }
}

// QKV projection (fp32 math) -> bf16 q / k(padded) / vT(padded).
__global__ __launch_bounds__(256) void qkv_gemm(
    const float* __restrict__ hidden, const float* __restrict__ Wq,
    const float* __restrict__ Wk, const float* __restrict__ Wv,
    const float* __restrict__ bq, const float* __restrict__ bk,
    const float* __restrict__ bv, unsigned short* __restrict__ qws,
    unsigned short* __restrict__ kws, unsigned short* __restrict__ vt) {
  __shared__ float At[32][68];
  __shared__ float Bs[32][68];
  int m0 = blockIdx.x * 64;
  int n0 = blockIdx.y * 64;
  int w = n0 / HID;
  int nc0 = n0 % HID;
  const float* W = (w == 0) ? Wq : (w == 1 ? Wk : Wv);
  const float* bias = (w == 0) ? bq : (w == 1 ? bk : bv);
  int t = threadIdx.x;
  int tx = t & 15, ty = t >> 4;
  float acc[4][4] = {};
  for (int k0 = 0; k0 < HID; k0 += 32) {
#pragma unroll
    for (int u = 0; u < 2; ++u) {
      int f = t * 2 + u;
      int r = f >> 3, c4 = f & 7;
      float4 av = *(const float4*)(hidden + (size_t)(m0 + r) * HID + k0 + c4 * 4);
      At[c4 * 4 + 0][r] = av.x; At[c4 * 4 + 1][r] = av.y;
      At[c4 * 4 + 2][r] = av.z; At[c4 * 4 + 3][r] = av.w;
    }
#pragma unroll
    for (int u = 0; u < 2; ++u) {
      int f = t * 2 + u;
      int kk = f >> 4, c4 = f & 15;
      float4 bv4 = *(const float4*)(W + (size_t)(k0 + kk) * HID + nc0 + c4 * 4);
      *(float4*)&Bs[kk][c4 * 4] = bv4;
    }
    __syncthreads();
#pragma unroll
    for (int kk = 0; kk < 32; ++kk) {
      float4 a4 = *(const float4*)&At[kk][ty * 4];
      float4 b4 = *(const float4*)&Bs[kk][tx * 4];
      float av[4] = {a4.x, a4.y, a4.z, a4.w};
      float bvv[4] = {b4.x, b4.y, b4.z, b4.w};
#pragma unroll
      for (int i = 0; i < 4; ++i)
#pragma unroll
        for (int jj = 0; jj < 4; ++jj) acc[i][jj] += av[i] * bvv[jj];
    }
    __syncthreads();
  }
  int h = nc0 >> 6;
#pragma unroll
  for (int i = 0; i < 4; ++i) {
    int gm = m0 + ty * 4 + i;
    int bl = gm >> 13, s = gm & 8191;
    size_t bh = (size_t)bl * NHEADS + h;
    float v0 = acc[i][0] + bias[nc0 + tx * 4 + 0];
    float v1 = acc[i][1] + bias[nc0 + tx * 4 + 1];
    float v2 = acc[i][2] + bias[nc0 + tx * 4 + 2];
    float v3 = acc[i][3] + bias[nc0 + tx * 4 + 3];
    if (w == 0) {
      ushort4 o = {f2bf(v0), f2bf(v1), f2bf(v2), f2bf(v3)};
      *(ushort4*)(qws + (bh * SEQ + s) * HDIM + tx * 4) = o;
    } else if (w == 1) {
      ushort4 o = {f2bf(v0), f2bf(v1), f2bf(v2), f2bf(v3)};
      *(ushort4*)(kws + (bh * SPAD + s + BSZ) * HDIM + tx * 4) = o;
    } else {
      size_t vb = bh * (size_t)(HDIM * SPAD) + (size_t)(s + BSZ);
      vt[vb + (size_t)(tx * 4 + 0) * SPAD] = f2bf(v0);
      vt[vb + (size_t)(tx * 4 + 1) * SPAD] = f2bf(v1);
      vt[vb + (size_t)(tx * 4 + 2) * SPAD] = f2bf(v2);
      vt[vb + (size_t)(tx * 4 + 3) * SPAD] = f2bf(v3);
    }
  }
}

// ---------------------------------------------------------------------------
// MFMA attention. Block = (b,h,n). 512 thr = 8 waves. Wave owns q-strip of 16.
__global__ __launch_bounds__(512, 2) void attn_kernel(
    const unsigned short* __restrict__ qws, const unsigned short* __restrict__ kws,
    const unsigned short* __restrict__ vt, const unsigned short* __restrict__ posq,
    const unsigned short* __restrict__ posk, unsigned short* __restrict__ ctx) {
  extern __shared__ char smem[];
  int* iLUT = (int*)(smem + LUT_OFF);
  unsigned short* C2P = (unsigned short*)(smem + C2P_OFF);
  unsigned short* Tl = (unsigned short*)(smem + T_OFF);

  const int tid = threadIdx.x;
  const int wave = tid >> 6;
  const int lane = tid & 63;
  const int l15 = lane & 15;
  const int g = lane >> 4;
  const int qs = wave << 4;

  const int n = blockIdx.x & 63;
  const int bh = blockIdx.x >> 6;
  const int h = bh % NHEADS;
  const int b = bh / NHEADS;

  const unsigned short* qsrc = qws + ((size_t)bh * SEQ + n * BSZ) * HDIM;
  const unsigned short* ksrc = kws + ((size_t)bh * SPAD + n * BSZ) * HDIM;
  const unsigned short* vtsrc = vt + (size_t)bh * (HDIM * SPAD) + n * BSZ;
  const unsigned short* pqh = posq + (size_t)h * PBUCK * HDIM;
  const unsigned short* pkh = posk + (size_t)h * PBUCK * HDIM;

  // ---- phase 0: stage Q, posk half 0, fill LUT
  for (int idx = tid; idx < 128 * 8; idx += 512) {
    int row = idx >> 3, c = idx & 7;
    uint4 v = *(const uint4*)(qsrc + row * HDIM + c * 8);
    *(uint4*)(smem + Q_OFF + row * 128 + ((c * 16) ^ ((row & 7) << 4))) = v;
  }
  for (int idx = tid; idx < 192 * 8; idx += 512) {
    int row = idx >> 3, c = idx & 7;
    uint4 v = *(const uint4*)(pkh + row * HDIM + c * 8);
    *(uint4*)(smem + PKH_OFF + row * 128 + ((c * 16) ^ ((row & 7) << 4))) = v;
  }
  if (tid < 511) iLUT[tid] = bucket_idx(tid - 383);
  __syncthreads();

  // Q fragments for this wave's q-strip (used as A for C2P, as B for QK^T)
  bf16x8 qf0 = ldfrag(smem, Q_OFF, qs + l15, 128, 0, g);
  bf16x8 qf1 = ldfrag(smem, Q_OFF, qs + l15, 128, 1, g);

  // ---- phase 1: C2P_all[q][p] = Q . posk^T  (two halves of 192 p)
#pragma unroll
  for (int half = 0; half < 2; ++half) {
    if (half) {
      __syncthreads();
      for (int idx = tid; idx < 192 * 8; idx += 512) {
        int row = idx >> 3, c = idx & 7;
        uint4 v = *(const uint4*)(pkh + (192 + row) * HDIM + c * 8);
        *(uint4*)(smem + PKH_OFF + row * 128 + ((c * 16) ^ ((row & 7) << 4))) = v;
      }
      __syncthreads();
    }
    for (int ntl = 0; ntl < 12; ++ntl) {
      bf16x8 b0 = ldfrag(smem, PKH_OFF, 16 * ntl + l15, 128, 0, g);
      bf16x8 b1 = ldfrag(smem, PKH_OFF, 16 * ntl + l15, 128, 1, g);
      f32x4 c = {0.f, 0.f, 0.f, 0.f};
      c = MFMA16(qf0, b0, c);
      c = MFMA16(qf1, b1, c);
      int p = half * 192 + 16 * ntl + l15;
#pragma unroll
      for (int r = 0; r < 4; ++r)
        C2P[(qs + 4 * g + r) * 392 + p] = f2bf(c[r]);
    }
  }
  __syncthreads();

  // ---- phase 2: S accumulators init with gathered c2p
  f32x4 acc[24];
#pragma unroll
  for (int t = 0; t < 24; ++t) acc[t] = (f32x4){0.f, 0.f, 0.f, 0.f};
  {
    const int qrow = qs + l15;
    const unsigned short* c2pRow = C2P + qrow * 392;
    const int dbase = qrow - 4 * g + 383;
#pragma unroll
    for (int t = 0; t < 24; ++t) {
#pragma unroll
      for (int r = 0; r < 4; ++r) {
        int idx = iLUT[dbase - 16 * t - r];
        acc[t][r] += bf2f(c2pRow[idx]);
      }
    }
  }
  __syncthreads();  // C2P dead

  // ---- phase 3: stage K and posq (full 384)
  for (int idx = tid; idx < 384 * 8; idx += 512) {
    int row = idx >> 3, c = idx & 7;
    uint4 v = *(const uint4*)(ksrc + row * HDIM + c * 8);
    *(uint4*)(smem + K_OFF + row * 128 + ((c * 16) ^ ((row & 7) << 4))) = v;
  }
  for (int idx = tid; idx < 384 * 8; idx += 512) {
    int row = idx >> 3, c = idx & 7;
    uint4 v = *(const uint4*)(pqh + row * HDIM + c * 8);
    *(uint4*)(smem + PQ_OFF + row * 128 + ((c * 16) ^ ((row & 7) << 4))) = v;
  }
  __syncthreads();

  // ---- phase 4: p2c, 12 subtiles of 32 kwin
#pragma unroll
  for (int s = 0; s < 12; ++s) {
    const int lo = iLUT[352 - 32 * s];
    const int hi = iLUT[510 - 32 * s];
    const int ntiles = ((hi - lo + 1) + 15) >> 4;
    for (int tl = wave; tl < 2 * ntiles; tl += 8) {
      int mt = tl & 1, ntl = tl >> 1;
      bf16x8 a0 = ldfrag(smem, K_OFF, 32 * s + 16 * mt + l15, 128, 0, g);
      bf16x8 a1 = ldfrag(smem, K_OFF, 32 * s + 16 * mt + l15, 128, 1, g);
      int prow = lo + 16 * ntl + l15;
      prow = prow > 383 ? 383 : prow;
      bf16x8 b0 = ldfrag(smem, PQ_OFF, prow, 128, 0, g);
      bf16x8 b1 = ldfrag(smem, PQ_OFF, prow, 128, 1, g);
      f32x4 c = {0.f, 0.f, 0.f, 0.f};
      c = MFMA16(a0, b0, c);
      c = MFMA16(a1, b1, c);
#pragma unroll
      for (int r = 0; r < 4; ++r)
        Tl[(16 * mt + 4 * g + r) * 184 + 16 * ntl + l15] = f2bf(c[r]);
    }
    __syncthreads();
    {
      const int dbase2 = qs + l15 - 32 * s - 4 * g + 383;
#pragma unroll
      for (int tt = 0; tt < 2; ++tt) {
#pragma unroll
        for (int r = 0; r < 4; ++r) {
          int idx = iLUT[dbase2 - 16 * tt - r];
          acc[2 * s + tt][r] += bf2f(Tl[(16 * tt + 4 * g + r) * 184 + idx - lo]);
        }
      }
    }
    __syncthreads();
  }

  // ---- phase 5: QK^T accumulate (A = K rows, B = Q^T)
#pragma unroll
  for (int t = 0; t < 24; ++t) {
    bf16x8 a0 = ldfrag(smem, K_OFF, 16 * t + l15, 128, 0, g);
    bf16x8 a1 = ldfrag(smem, K_OFF, 16 * t + l15, 128, 1, g);
    acc[t] = MFMA16(a0, qf0, acc[t]);
    acc[t] = MFMA16(a1, qf1, acc[t]);
  }
  __syncthreads();  // posq region dead; about to become Vt

  // ---- phase 6: stage Vt (loads in flight under softmax)
  for (int idx = tid; idx < 64 * 48; idx += 512) {
    int row = idx / 48, c = idx - row * 48;
    uint4 v = *(const uint4*)(vtsrc + (size_t)row * SPAD + c * 8);
    *(uint4*)(smem + VT_OFF + row * 768 + ((c * 16) ^ ((row & 7) << 4))) = v;
  }

  // ---- phase 7: softmax (in-register; q = qs + l15 fixed per lane)
  float m = -1e30f;
#pragma unroll
  for (int t = 0; t < 24; ++t)
#pragma unroll
    for (int r = 0; r < 4; ++r) m = fmaxf(m, acc[t][r]);
  m = fmaxf(m, __shfl_xor(m, 16));
  m = fmaxf(m, __shfl_xor(m, 32));
  float sum = 0.f;
#pragma unroll
  for (int t = 0; t < 24; ++t)
#pragma unroll
    for (int r = 0; r < 4; ++r) {
      float p = exp2f((acc[t][r] - m) * 0.10411790f);  // /sqrt(192) * log2e
      acc[t][r] = p;
      sum += p;
    }
  sum += __shfl_xor(sum, 16);
  sum += __shfl_xor(sum, 32);
  float inv = 1.0f / sum;

  bf16x8 pa[12];
#pragma unroll
  for (int kt = 0; kt < 12; ++kt) {
    union { bf16x8 v; unsigned short u[8]; } w;
#pragma unroll
    for (int j = 0; j < 4; ++j) w.u[j] = f2bf(acc[2 * kt][j] * inv);
#pragma unroll
    for (int j = 0; j < 4; ++j) w.u[4 + j] = f2bf(acc[2 * kt + 1][j] * inv);
    pa[kt] = w.v;
  }
  __syncthreads();  // Vt staged

  // ---- phase 8: PV (A = P frags, B = Vt rows), write ctx bf16
  unsigned short* ctxg = ctx + ((size_t)b * SEQ + n * BSZ) * HID + h * HDIM;
#pragma unroll
  for (int nt = 0; nt < 4; ++nt) {
    f32x4 o = {0.f, 0.f, 0.f, 0.f};
#pragma unroll
    for (int kt = 0; kt < 12; ++kt) {
      bf16x8 bv = ldfrag(smem, VT_OFF, 16 * nt + l15, 768, kt, g);
      o = MFMA16(pa[kt], bv, o);
    }
#pragma unroll
    for (int r = 0; r < 4; ++r) {
      size_t off = (size_t)(qs + 4 * g + r) * HID + 16 * nt + l15;
      ctxg[off] = f2bf(o[r]);
    }
  }
}

// Out projection + residual: out = ctx(bf16) @ Wo + bo + hidden
__global__ __launch_bounds__(256) void out_gemm(
    const unsigned short* __restrict__ ctx, const float* __restrict__ Wo,
    const float* __restrict__ bo, const float* __restrict__ hidden,
    float* __restrict__ out) {
  __shared__ float At[32][68];
  __shared__ float Bs[32][68];
  int m0 = blockIdx.x * 64;
  int n0 = blockIdx.y * 64;
  int t = threadIdx.x;
  int tx = t & 15, ty = t >> 4;
  float acc[4][4] = {};
  for (int k0 = 0; k0 < HID; k0 += 32) {
#pragma unroll
    for (int u = 0; u < 2; ++u) {
      int f = t * 2 + u;
      int r = f >> 3, c4 = f & 7;
      ushort4 us = *(const ushort4*)(ctx + (size_t)(m0 + r) * HID + k0 + c4 * 4);
      At[c4 * 4 + 0][r] = bf2f(us.x);
      At[c4 * 4 + 1][r] = bf2f(us.y);
      At[c4 * 4 + 2][r] = bf2f(us.z);
      At[c4 * 4 + 3][r] = bf2f(us.w);
    }
#pragma unroll
    for (int u = 0; u < 2; ++u) {
      int f = t * 2 + u;
      int kk = f >> 4, c4 = f & 15;
      float4 bv4 = *(const float4*)(Wo + (size_t)(k0 + kk) * HID + n0 + c4 * 4);
      *(float4*)&Bs[kk][c4 * 4] = bv4;
    }
    __syncthreads();
#pragma unroll
    for (int kk = 0; kk < 32; ++kk) {
      float4 a4 = *(const float4*)&At[kk][ty * 4];
      float4 b4 = *(const float4*)&Bs[kk][tx * 4];
      float av[4] = {a4.x, a4.y, a4.z, a4.w};
      float bvv[4] = {b4.x, b4.y, b4.z, b4.w};
#pragma unroll
      for (int i = 0; i < 4; ++i)
#pragma unroll
        for (int jj = 0; jj < 4; ++jj) acc[i][jj] += av[i] * bvv[jj];
    }
    __syncthreads();
  }
#pragma unroll
  for (int i = 0; i < 4; ++i) {
    int gm = m0 + ty * 4 + i;
#pragma unroll
    for (int jj = 0; jj < 4; ++jj) {
      int nc = n0 + tx * 4 + jj;
      out[(size_t)gm * HID + nc] = acc[i][jj] + bo[nc] + hidden[(size_t)gm * HID + nc];
    }
  }
}

__global__ __launch_bounds__(256) void ln_kernel(float* __restrict__ x,
                                                 const float* __restrict__ sc,
                                                 const float* __restrict__ bi) {
  __shared__ float red[8];
  int row = blockIdx.x;
  int t = threadIdx.x;
  float* xr = x + (size_t)row * HID;
  float e0 = xr[t], e1 = xr[t + 256], e2 = xr[t + 512];
  float ssum = e0 + e1 + e2;
#pragma unroll
  for (int o = 1; o < 64; o <<= 1) ssum += __shfl_xor(ssum, o);
  int w = t >> 6;
  if ((t & 63) == 0) red[w] = ssum;
  __syncthreads();
  float mu = (red[0] + red[1] + red[2] + red[3]) * (1.0f / 768.0f);
  float d0 = e0 - mu, d1 = e1 - mu, d2 = e2 - mu;
  float sq = d0 * d0 + d1 * d1 + d2 * d2;
#pragma unroll
  for (int o = 1; o < 64; o <<= 1) sq += __shfl_xor(sq, o);
  __syncthreads();
  if ((t & 63) == 0) red[4 + w] = sq;
  __syncthreads();
  float var = (red[4] + red[5] + red[6] + red[7]) * (1.0f / 768.0f);
  float rstd = 1.0f / sqrtf(var + 1e-7f);
  xr[t] = d0 * rstd * sc[t] + bi[t];
  xr[t + 256] = d1 * rstd * sc[t + 256] + bi[t + 256];
  xr[t + 512] = d2 * rstd * sc[t + 512] + bi[t + 512];
}

extern "C" void kernel_launch(void* const* d_in, const int* in_sizes, int n_in,
                              void* d_out, int out_size, void* d_ws,
                              size_t ws_size, hipStream_t stream) {
  (void)in_sizes; (void)n_in; (void)out_size; (void)ws_size;
  const float* hidden = (const float*)d_in[0];
  const float* relpos = (const float*)d_in[1];
  const float* Wq = (const float*)d_in[2];
  const float* bq = (const float*)d_in[3];
  const float* Wk = (const float*)d_in[4];
  const float* bk = (const float*)d_in[5];
  const float* Wv = (const float*)d_in[6];
  const float* bv = (const float*)d_in[7];
  const float* Wo = (const float*)d_in[8];
  const float* bo = (const float*)d_in[9];
  const float* lns = (const float*)d_in[10];
  const float* lnb = (const float*)d_in[11];
  float* out = (float*)d_out;

  // Workspace (ushorts): q | k | vt | ctx | posq | posk  = 196.5 MiB total
  unsigned short* ws = (unsigned short*)d_ws;
  const size_t QE = (size_t)48 * SEQ * HDIM;     // 25,165,824
  const size_t KE = (size_t)48 * SPAD * HDIM;    // 25,952,256
  unsigned short* qws = ws;
  unsigned short* kws = qws + QE;
  unsigned short* vt = kws + KE;
  unsigned short* ctx = vt + KE;
  unsigned short* posq = ctx + QE;
  unsigned short* posk = posq + (size_t)NHEADS * PBUCK * HDIM;

  static bool attrib_set = false;
  if (!attrib_set) {
    hipFuncSetAttribute((const void*)attn_kernel,
                        hipFuncAttributeMaxDynamicSharedMemorySize, SMEM_BYTES);
    attrib_set = true;
  }

  pos_gemm<<<dim3(8, 24), 256, 0, stream>>>(relpos, Wq, Wk, bq, bk, posq, posk);
  zero_halo<<<3072, 256, 0, stream>>>(kws, vt);
  qkv_gemm<<<dim3(512, 36), 256, 0, stream>>>(hidden, Wq, Wk, Wv, bq, bk, bv,
                                              qws, kws, vt);
  attn_kernel<<<3072, 512, SMEM_BYTES, stream>>>(qws, kws, vt, posq, posk, ctx);
  out_gemm<<<dim3(512, 12), 256, 0, stream>>>(ctx, Wo, bo, hidden, out);
  ln_kernel<<<32768, 256, 0, stream>>>(out, lns, lnb);
}

// Round 4
// 862.670 us; speedup vs baseline: 20.8654x; 2.9674x over previous
//
#include <hip/hip_runtime.h>
#include <math.h>

// ---------------------------------------------------------------------------
// LocalSlidingWindow_DisentangledAttention — Round 4: MFMA everywhere.
// B=4, S=8192, H=768, NH=12, HD=64, BS=128, WIN=384, BUCKETS=256.
//
// conv_wt    : W fp32 [768][768] -> bf16 W^T rows (WqkvT / WoT, aliased)
// pos_gemm   : fp32 math -> bf16 posq/posk [h,512,64]
// qkv_mfma   : bf16 MFMA 128x128xBK64 -> q[bh,s,d], k[bh,s,d], vT[bh,d,s]
//              (NO halo padding; attn staging zero-fills out-of-range)
// attn_kernel: per (b,h,n) block, 8 waves, mfma_f32_16x16x32_bf16
// out_mfma   : ctx(bf16) @ WoT + bo + hidden -> fp32 out
// ln_kernel  : in-place LayerNorm
// ---------------------------------------------------------------------------

#define NHEADS 12
#define HDIM   64
#define SEQ    8192
#define HID    768
#define BSZ    128
#define WIN    384
#define PBUCK  512

typedef __attribute__((ext_vector_type(8))) short bf16x8;
typedef __attribute__((ext_vector_type(4))) float f32x4;
#define MFMA16(a, b, c) __builtin_amdgcn_mfma_f32_16x16x32_bf16((a), (b), (c), 0, 0, 0)

// LDS byte map for attn (dynamic, 155136 total)
#define C2P_OFF 0        // [128][392] bf16 = 100352   (phase 1-2)
#define K_OFF   0        // [384][64]  bf16 = 49152    (phase 3+)
#define PQ_OFF  49152    // [384][64]  bf16 = 49152    (phase 3-4)
#define VT_OFF  49152    // [64][384]  bf16 = 49152    (PV phase)
#define T_OFF   100352   // [32][184]  bf16 = 11776
#define Q_OFF   112128   // [128][64]  bf16 = 16384
#define PKH_OFF 128512   // [192][64]  bf16 = 24576
#define LUT_OFF 153088   // [511] int  = 2044
#define SMEM_BYTES 155136

__device__ __forceinline__ unsigned short f2bf(float f) {
  unsigned int x = __builtin_bit_cast(unsigned int, f);
  unsigned int r = (x + 0x7FFFu + ((x >> 16) & 1u)) >> 16;
  return (unsigned short)r;
}
__device__ __forceinline__ float bf2f(unsigned short u) {
  unsigned int x = ((unsigned int)u) << 16;
  return __builtin_bit_cast(float, x);
}

// idx(rel) for rel in [-383, 127]
__device__ __forceinline__ int bucket_idx(int rel) {
  if (rel >= -128) return rel + 256;
  float a = (float)(-rel);
  float t = logf(a * (1.0f / 128.0f));
  t = t / 0.6892332813f;
  t = t * 127.0f;
  int lp = (int)(ceilf(t) + 128.0f);
  int r = 256 - lp;
  return r < 0 ? 0 : r;
}

// Fragment load from swizzled row-major bf16 LDS tile (attn variant).
__device__ __forceinline__ bf16x8 ldfrag(const char* sm, int byteBase, int row,
                                         int rowBytes, int slice, int g) {
  const int swz = (row & 7) << 4;
  const char* p = sm + byteBase + row * rowBytes;
  union { bf16x8 v; uint2 u2[2]; } w;
  w.u2[0] = *(const uint2*)(p + (((slice << 6) + (g << 3)) ^ swz));
  w.u2[1] = *(const uint2*)(p + (((slice << 6) + 32 + (g << 3)) ^ swz));
  return w.v;
}

// ---------------------------------------------------------------------------
// Weight transpose fp32 -> bf16: Wt[z*768 + n][k] = W_z[k][n]
__global__ __launch_bounds__(256) void conv_wt(const float* __restrict__ W0,
                                               const float* __restrict__ W1,
                                               const float* __restrict__ W2,
                                               unsigned short* __restrict__ Wt) {
  __shared__ float tile[64][65];
  int bx = blockIdx.x, by = blockIdx.y, z = blockIdx.z;
  const float* W = (z == 0) ? W0 : (z == 1 ? W1 : W2);
  int t = threadIdx.x;
  int c = t & 63, r0 = (t >> 6) * 16;
#pragma unroll
  for (int rr = 0; rr < 16; ++rr)
    tile[r0 + rr][c] = W[(size_t)(by * 64 + r0 + rr) * HID + bx * 64 + c];
  __syncthreads();
#pragma unroll
  for (int rr = 0; rr < 16; ++rr) {
    int nw = r0 + rr;
    Wt[((size_t)z * HID + bx * 64 + nw) * HID + by * 64 + c] = f2bf(tile[c][nw]);
  }
}

// Positional projection (fp32 math) -> bf16 posq/posk [h][512][64]
__global__ __launch_bounds__(256) void pos_gemm(
    const float* __restrict__ relpos, const float* __restrict__ Wq,
    const float* __restrict__ Wk, const float* __restrict__ bq,
    const float* __restrict__ bk, unsigned short* __restrict__ posq,
    unsigned short* __restrict__ posk) {
  __shared__ float At[32][68];
  __shared__ float Bs[32][68];
  int m0 = blockIdx.x * 64;
  int n0 = blockIdx.y * 64;
  int w = n0 / HID;
  int nc0 = n0 % HID;
  const float* W = (w == 0) ? Wq : Wk;
  const float* bias = (w == 0) ? bq : bk;
  int t = threadIdx.x;
  int tx = t & 15, ty = t >> 4;
  float acc[4][4] = {};
  for (int k0 = 0; k0 < HID; k0 += 32) {
#pragma unroll
    for (int u = 0; u < 2; ++u) {
      int f = t * 2 + u;
      int r = f >> 3, c4 = f & 7;
      float4 av = *(const float4*)(relpos + (size_t)(m0 + r) * HID + k0 + c4 * 4);
      At[c4 * 4 + 0][r] = av.x; At[c4 * 4 + 1][r] = av.y;
      At[c4 * 4 + 2][r] = av.z; At[c4 * 4 + 3][r] = av.w;
    }
#pragma unroll
    for (int u = 0; u < 2; ++u) {
      int f = t * 2 + u;
      int kk = f >> 4, c4 = f & 15;
      float4 bv4 = *(const float4*)(W + (size_t)(k0 + kk) * HID + nc0 + c4 * 4);
      *(float4*)&Bs[kk][c4 * 4] = bv4;
    }
    __syncthreads();
#pragma unroll
    for (int kk = 0; kk < 32; ++kk) {
      float4 a4 = *(const float4*)&At[kk][ty * 4];
      float4 b4 = *(const float4*)&Bs[kk][tx * 4];
      float av[4] = {a4.x, a4.y, a4.z, a4.w};
      float bvv[4] = {b4.x, b4.y, b4.z, b4.w};
#pragma unroll
      for (int i = 0; i < 4; ++i)
#pragma unroll
        for (int jj = 0; jj < 4; ++jj) acc[i][jj] += av[i] * bvv[jj];
    }
    __syncthreads();
  }
  int h = nc0 >> 6;
  unsigned short* dst = (w == 0) ? posq : posk;
#pragma unroll
  for (int i = 0; i < 4; ++i) {
    int p = m0 + ty * 4 + i;
    ushort4 o;
    o.x = f2bf(acc[i][0] + bias[nc0 + tx * 4 + 0]);
    o.y = f2bf(acc[i][1] + bias[nc0 + tx * 4 + 1]);
    o.z = f2bf(acc[i][2] + bias[nc0 + tx * 4 + 2]);
    o.w = f2bf(acc[i][3] + bias[nc0 + tx * 4 + 3]);
    *(ushort4*)(dst + ((size_t)h * PBUCK + p) * HDIM + tx * 4) = o;
  }
}

// ---------------------------------------------------------------------------
// QKV projection, bf16 MFMA. Tile 128x128, BK=64, 256 thr = 4 waves (2x2).
// A = hidden fp32 (convert while staging), B = WqkvT bf16 rows.
__global__ __launch_bounds__(256) void qkv_mfma(
    const float* __restrict__ hidden, const unsigned short* __restrict__ Wt,
    const float* __restrict__ bq, const float* __restrict__ bk,
    const float* __restrict__ bv, unsigned short* __restrict__ qws,
    unsigned short* __restrict__ kws, unsigned short* __restrict__ vt) {
  __shared__ unsigned short As[8192];  // [128][64] swizzled 16B chunks
  __shared__ unsigned short Bs[8192];
  const int t = threadIdx.x;
  const int lane = t & 63;
  const int l15 = lane & 15, g = lane >> 4;
  const int wave = t >> 6;
  const int wy = wave >> 1, wx = wave & 1;
  const int n0 = blockIdx.x * 128;
  const int m0 = blockIdx.y * 128;

  f32x4 acc[4][4];
#pragma unroll
  for (int i = 0; i < 4; ++i)
#pragma unroll
    for (int j = 0; j < 4; ++j) acc[i][j] = (f32x4){0.f, 0.f, 0.f, 0.f};

  for (int k0 = 0; k0 < HID; k0 += 64) {
#pragma unroll
    for (int i = 0; i < 4; ++i) {
      int c = t + i * 256;
      int row = c >> 3, cx = c & 7;
      const float4* src =
          (const float4*)(hidden + (size_t)(m0 + row) * HID + k0 + cx * 8);
      float4 a = src[0], b = src[1];
      union { bf16x8 v; unsigned short u[8]; } w;
      w.u[0] = f2bf(a.x); w.u[1] = f2bf(a.y); w.u[2] = f2bf(a.z); w.u[3] = f2bf(a.w);
      w.u[4] = f2bf(b.x); w.u[5] = f2bf(b.y); w.u[6] = f2bf(b.z); w.u[7] = f2bf(b.w);
      *(bf16x8*)((char*)As + row * 128 + ((cx * 16) ^ ((row & 7) << 4))) = w.v;
    }
#pragma unroll
    for (int i = 0; i < 4; ++i) {
      int c = t + i * 256;
      int row = c >> 3, cx = c & 7;
      uint4 v = *(const uint4*)(Wt + (size_t)(n0 + row) * HID + k0 + cx * 8);
      *(uint4*)((char*)Bs + row * 128 + ((cx * 16) ^ ((row & 7) << 4))) = v;
    }
    __syncthreads();
    bf16x8 af[4][2], bf[4][2];
#pragma unroll
    for (int mt = 0; mt < 4; ++mt) {
      int row = wy * 64 + mt * 16 + l15;
      const char* p = (const char*)As + row * 128;
      int swz = (row & 7) << 4;
#pragma unroll
      for (int s = 0; s < 2; ++s)
        af[mt][s] = *(const bf16x8*)(p + ((s * 64 + g * 16) ^ swz));
    }
#pragma unroll
    for (int nt = 0; nt < 4; ++nt) {
      int row = wx * 64 + nt * 16 + l15;
      const char* p = (const char*)Bs + row * 128;
      int swz = (row & 7) << 4;
#pragma unroll
      for (int s = 0; s < 2; ++s)
        bf[nt][s] = *(const bf16x8*)(p + ((s * 64 + g * 16) ^ swz));
    }
#pragma unroll
    for (int mt = 0; mt < 4; ++mt)
#pragma unroll
      for (int nt = 0; nt < 4; ++nt) {
        acc[mt][nt] = MFMA16(af[mt][0], bf[nt][0], acc[mt][nt]);
        acc[mt][nt] = MFMA16(af[mt][1], bf[nt][1], acc[mt][nt]);
      }
    __syncthreads();
  }

  // Epilogue: D(m = ..+4g+r, n = ..+l15); scatter to q/k/vT bf16.
  const int w = n0 / HID;  // 0:q 1:k 2:v (block n-range within one matrix)
  const float* bias = (w == 0) ? bq : (w == 1 ? bk : bv);
#pragma unroll
  for (int nt = 0; nt < 4; ++nt) {
    int gn = n0 + wx * 64 + nt * 16 + l15;
    int nc = gn - w * HID;
    int h = nc >> 6, d = nc & 63;
    float bval = bias[nc];
#pragma unroll
    for (int mt = 0; mt < 4; ++mt) {
      f32x4 a = acc[mt][nt];
#pragma unroll
      for (int r = 0; r < 4; ++r) {
        int m = m0 + wy * 64 + mt * 16 + 4 * g + r;
        int bl = m >> 13, s = m & 8191;
        size_t bh = (size_t)bl * NHEADS + h;
        unsigned short val = f2bf(a[r] + bval);
        if (w == 0)
          qws[(bh * SEQ + s) * HDIM + d] = val;
        else if (w == 1)
          kws[(bh * SEQ + s) * HDIM + d] = val;
        else
          vt[bh * ((size_t)HDIM * SEQ) + (size_t)d * SEQ + s] = val;
      }
    }
  }
}

// ---------------------------------------------------------------------------
// MFMA attention. Block = (b,h,n). 512 thr = 8 waves. Wave owns q-strip of 16.
__global__ __launch_bounds__(512, 2) void attn_kernel(
    const unsigned short* __restrict__ qws, const unsigned short* __restrict__ kws,
    const unsigned short* __restrict__ vt, const unsigned short* __restrict__ posq,
    const unsigned short* __restrict__ posk, unsigned short* __restrict__ ctx) {
  extern __shared__ char smem[];
  int* iLUT = (int*)(smem + LUT_OFF);
  unsigned short* C2P = (unsigned short*)(smem + C2P_OFF);
  unsigned short* Tl = (unsigned short*)(smem + T_OFF);

  const int tid = threadIdx.x;
  const int wave = tid >> 6;
  const int lane = tid & 63;
  const int l15 = lane & 15;
  const int g = lane >> 4;
  const int qs = wave << 4;

  const int n = blockIdx.x & 63;
  const int bh = blockIdx.x >> 6;
  const int h = bh % NHEADS;
  const int b = bh / NHEADS;

  const unsigned short* qsrc = qws + ((size_t)bh * SEQ + n * BSZ) * HDIM;
  const unsigned short* kbh = kws + (size_t)bh * SEQ * HDIM;
  const unsigned short* vtbh = vt + (size_t)bh * ((size_t)HDIM * SEQ);
  const unsigned short* pqh = posq + (size_t)h * PBUCK * HDIM;
  const unsigned short* pkh = posk + (size_t)h * PBUCK * HDIM;

  // ---- phase 0: stage Q, posk half 0, fill LUT
  for (int idx = tid; idx < 128 * 8; idx += 512) {
    int row = idx >> 3, c = idx & 7;
    uint4 v = *(const uint4*)(qsrc + row * HDIM + c * 8);
    *(uint4*)(smem + Q_OFF + row * 128 + ((c * 16) ^ ((row & 7) << 4))) = v;
  }
  for (int idx = tid; idx < 192 * 8; idx += 512) {
    int row = idx >> 3, c = idx & 7;
    uint4 v = *(const uint4*)(pkh + row * HDIM + c * 8);
    *(uint4*)(smem + PKH_OFF + row * 128 + ((c * 16) ^ ((row & 7) << 4))) = v;
  }
  if (tid < 511) iLUT[tid] = bucket_idx(tid - 383);
  __syncthreads();

  bf16x8 qf0 = ldfrag(smem, Q_OFF, qs + l15, 128, 0, g);
  bf16x8 qf1 = ldfrag(smem, Q_OFF, qs + l15, 128, 1, g);

  // ---- phase 1: C2P_all[q][p] = Q . posk^T  (two halves of 192 p)
#pragma unroll
  for (int half = 0; half < 2; ++half) {
    if (half) {
      __syncthreads();
      for (int idx = tid; idx < 192 * 8; idx += 512) {
        int row = idx >> 3, c = idx & 7;
        uint4 v = *(const uint4*)(pkh + (192 + row) * HDIM + c * 8);
        *(uint4*)(smem + PKH_OFF + row * 128 + ((c * 16) ^ ((row & 7) << 4))) = v;
      }
      __syncthreads();
    }
    for (int ntl = 0; ntl < 12; ++ntl) {
      bf16x8 b0 = ldfrag(smem, PKH_OFF, 16 * ntl + l15, 128, 0, g);
      bf16x8 b1 = ldfrag(smem, PKH_OFF, 16 * ntl + l15, 128, 1, g);
      f32x4 c = {0.f, 0.f, 0.f, 0.f};
      c = MFMA16(qf0, b0, c);
      c = MFMA16(qf1, b1, c);
      int p = half * 192 + 16 * ntl + l15;
#pragma unroll
      for (int r = 0; r < 4; ++r)
        C2P[(qs + 4 * g + r) * 392 + p] = f2bf(c[r]);
    }
  }
  __syncthreads();

  // ---- phase 2: S accumulators init with gathered c2p
  f32x4 acc[24];
#pragma unroll
  for (int t = 0; t < 24; ++t) acc[t] = (f32x4){0.f, 0.f, 0.f, 0.f};
  {
    const int qrow = qs + l15;
    const unsigned short* c2pRow = C2P + qrow * 392;
    const int dbase = qrow - 4 * g + 383;
#pragma unroll
    for (int t = 0; t < 24; ++t) {
#pragma unroll
      for (int r = 0; r < 4; ++r) {
        int idx = iLUT[dbase - 16 * t - r];
        acc[t][r] += bf2f(c2pRow[idx]);
      }
    }
  }
  __syncthreads();  // C2P dead

  // ---- phase 3: stage K and posq (zero-fill outside [0,SEQ))
  for (int idx = tid; idx < 384 * 8; idx += 512) {
    int row = idx >> 3, c = idx & 7;
    int ks = n * BSZ - BSZ + row;
    uint4 v = make_uint4(0u, 0u, 0u, 0u);
    if (ks >= 0 && ks < SEQ) v = *(const uint4*)(kbh + (size_t)ks * HDIM + c * 8);
    *(uint4*)(smem + K_OFF + row * 128 + ((c * 16) ^ ((row & 7) << 4))) = v;
  }
  for (int idx = tid; idx < 384 * 8; idx += 512) {
    int row = idx >> 3, c = idx & 7;
    uint4 v = *(const uint4*)(pqh + row * HDIM + c * 8);
    *(uint4*)(smem + PQ_OFF + row * 128 + ((c * 16) ^ ((row & 7) << 4))) = v;
  }
  __syncthreads();

  // ---- phase 4: p2c, 12 subtiles of 32 kwin
#pragma unroll
  for (int s = 0; s < 12; ++s) {
    const int lo = iLUT[352 - 32 * s];
    const int hi = iLUT[510 - 32 * s];
    const int ntiles = ((hi - lo + 1) + 15) >> 4;
    for (int tl = wave; tl < 2 * ntiles; tl += 8) {
      int mt = tl & 1, ntl = tl >> 1;
      bf16x8 a0 = ldfrag(smem, K_OFF, 32 * s + 16 * mt + l15, 128, 0, g);
      bf16x8 a1 = ldfrag(smem, K_OFF, 32 * s + 16 * mt + l15, 128, 1, g);
      int prow = lo + 16 * ntl + l15;
      prow = prow > 383 ? 383 : prow;
      bf16x8 b0 = ldfrag(smem, PQ_OFF, prow, 128, 0, g);
      bf16x8 b1 = ldfrag(smem, PQ_OFF, prow, 128, 1, g);
      f32x4 c = {0.f, 0.f, 0.f, 0.f};
      c = MFMA16(a0, b0, c);
      c = MFMA16(a1, b1, c);
#pragma unroll
      for (int r = 0; r < 4; ++r)
        Tl[(16 * mt + 4 * g + r) * 184 + 16 * ntl + l15] = f2bf(c[r]);
    }
    __syncthreads();
    {
      const int dbase2 = qs + l15 - 32 * s - 4 * g + 383;
#pragma unroll
      for (int tt = 0; tt < 2; ++tt) {
#pragma unroll
        for (int r = 0; r < 4; ++r) {
          int idx = iLUT[dbase2 - 16 * tt - r];
          acc[2 * s + tt][r] += bf2f(Tl[(16 * tt + 4 * g + r) * 184 + idx - lo]);
        }
      }
    }
    __syncthreads();
  }

  // ---- phase 5: QK^T accumulate (A = K rows, B = Q^T)
#pragma unroll
  for (int t = 0; t < 24; ++t) {
    bf16x8 a0 = ldfrag(smem, K_OFF, 16 * t + l15, 128, 0, g);
    bf16x8 a1 = ldfrag(smem, K_OFF, 16 * t + l15, 128, 1, g);
    acc[t] = MFMA16(a0, qf0, acc[t]);
    acc[t] = MFMA16(a1, qf1, acc[t]);
  }
  __syncthreads();  // posq region dead; about to become Vt

  // ---- phase 6: stage Vt (zero-fill outside [0,SEQ))
  for (int idx = tid; idx < 64 * 48; idx += 512) {
    int row = idx / 48, c = idx - row * 48;
    int col0 = n * BSZ - BSZ + c * 8;
    uint4 v = make_uint4(0u, 0u, 0u, 0u);
    if (col0 >= 0 && col0 < SEQ)
      v = *(const uint4*)(vtbh + (size_t)row * SEQ + col0);
    *(uint4*)(smem + VT_OFF + row * 768 + ((c * 16) ^ ((row & 7) << 4))) = v;
  }

  // ---- phase 7: softmax (in-register; q = qs + l15 fixed per lane)
  float m = -1e30f;
#pragma unroll
  for (int t = 0; t < 24; ++t)
#pragma unroll
    for (int r = 0; r < 4; ++r) m = fmaxf(m, acc[t][r]);
  m = fmaxf(m, __shfl_xor(m, 16));
  m = fmaxf(m, __shfl_xor(m, 32));
  float sum = 0.f;
#pragma unroll
  for (int t = 0; t < 24; ++t)
#pragma unroll
    for (int r = 0; r < 4; ++r) {
      float p = exp2f((acc[t][r] - m) * 0.10411790f);  // /sqrt(192) * log2e
      acc[t][r] = p;
      sum += p;
    }
  sum += __shfl_xor(sum, 16);
  sum += __shfl_xor(sum, 32);
  float inv = 1.0f / sum;

  bf16x8 pa[12];
#pragma unroll
  for (int kt = 0; kt < 12; ++kt) {
    union { bf16x8 v; unsigned short u[8]; } w;
#pragma unroll
    for (int j = 0; j < 4; ++j) w.u[j] = f2bf(acc[2 * kt][j] * inv);
#pragma unroll
    for (int j = 0; j < 4; ++j) w.u[4 + j] = f2bf(acc[2 * kt + 1][j] * inv);
    pa[kt] = w.v;
  }
  __syncthreads();  // Vt staged

  // ---- phase 8: PV, write ctx bf16
  unsigned short* ctxg = ctx + ((size_t)b * SEQ + n * BSZ) * HID + h * HDIM;
#pragma unroll
  for (int nt = 0; nt < 4; ++nt) {
    f32x4 o = {0.f, 0.f, 0.f, 0.f};
#pragma unroll
    for (int kt = 0; kt < 12; ++kt) {
      bf16x8 bv = ldfrag(smem, VT_OFF, 16 * nt + l15, 768, kt, g);
      o = MFMA16(pa[kt], bv, o);
    }
#pragma unroll
    for (int r = 0; r < 4; ++r) {
      size_t off = (size_t)(qs + 4 * g + r) * HID + 16 * nt + l15;
      ctxg[off] = f2bf(o[r]);
    }
  }
}

// ---------------------------------------------------------------------------
// Out projection bf16 MFMA + bias + residual -> fp32 out.
__global__ __launch_bounds__(256) void out_mfma(
    const unsigned short* __restrict__ ctx, const unsigned short* __restrict__ WoT,
    const float* __restrict__ bo, const float* __restrict__ hidden,
    float* __restrict__ out) {
  __shared__ unsigned short As[8192];
  __shared__ unsigned short Bs[8192];
  const int t = threadIdx.x;
  const int lane = t & 63;
  const int l15 = lane & 15, g = lane >> 4;
  const int wave = t >> 6;
  const int wy = wave >> 1, wx = wave & 1;
  const int n0 = blockIdx.x * 128;
  const int m0 = blockIdx.y * 128;

  f32x4 acc[4][4];
#pragma unroll
  for (int i = 0; i < 4; ++i)
#pragma unroll
    for (int j = 0; j < 4; ++j) acc[i][j] = (f32x4){0.f, 0.f, 0.f, 0.f};

  for (int k0 = 0; k0 < HID; k0 += 64) {
#pragma unroll
    for (int i = 0; i < 4; ++i) {
      int c = t + i * 256;
      int row = c >> 3, cx = c & 7;
      uint4 v = *(const uint4*)(ctx + (size_t)(m0 + row) * HID + k0 + cx * 8);
      *(uint4*)((char*)As + row * 128 + ((cx * 16) ^ ((row & 7) << 4))) = v;
    }
#pragma unroll
    for (int i = 0; i < 4; ++i) {
      int c = t + i * 256;
      int row = c >> 3, cx = c & 7;
      uint4 v = *(const uint4*)(WoT + (size_t)(n0 + row) * HID + k0 + cx * 8);
      *(uint4*)((char*)Bs + row * 128 + ((cx * 16) ^ ((row & 7) << 4))) = v;
    }
    __syncthreads();
    bf16x8 af[4][2], bf[4][2];
#pragma unroll
    for (int mt = 0; mt < 4; ++mt) {
      int row = wy * 64 + mt * 16 + l15;
      const char* p = (const char*)As + row * 128;
      int swz = (row & 7) << 4;
#pragma unroll
      for (int s = 0; s < 2; ++s)
        af[mt][s] = *(const bf16x8*)(p + ((s * 64 + g * 16) ^ swz));
    }
#pragma unroll
    for (int nt = 0; nt < 4; ++nt) {
      int row = wx * 64 + nt * 16 + l15;
      const char* p = (const char*)Bs + row * 128;
      int swz = (row & 7) << 4;
#pragma unroll
      for (int s = 0; s < 2; ++s)
        bf[nt][s] = *(const bf16x8*)(p + ((s * 64 + g * 16) ^ swz));
    }
#pragma unroll
    for (int mt = 0; mt < 4; ++mt)
#pragma unroll
      for (int nt = 0; nt < 4; ++nt) {
        acc[mt][nt] = MFMA16(af[mt][0], bf[nt][0], acc[mt][nt]);
        acc[mt][nt] = MFMA16(af[mt][1], bf[nt][1], acc[mt][nt]);
      }
    __syncthreads();
  }

#pragma unroll
  for (int nt = 0; nt < 4; ++nt) {
    int gn = n0 + wx * 64 + nt * 16 + l15;
    float bval = bo[gn];
#pragma unroll
    for (int mt = 0; mt < 4; ++mt) {
      f32x4 a = acc[mt][nt];
#pragma unroll
      for (int r = 0; r < 4; ++r) {
        int m = m0 + wy * 64 + mt * 16 + 4 * g + r;
        size_t off = (size_t)m * HID + gn;
        out[off] = a[r] + bval + hidden[off];
      }
    }
  }
}

// In-place LayerNorm over rows of 768.
__global__ __launch_bounds__(256) void ln_kernel(float* __restrict__ x,
                                                 const float* __restrict__ sc,
                                                 const float* __restrict__ bi) {
  __shared__ float red[8];
  int row = blockIdx.x;
  int t = threadIdx.x;
  float* xr = x + (size_t)row * HID;
  float e0 = xr[t], e1 = xr[t + 256], e2 = xr[t + 512];
  float ssum = e0 + e1 + e2;
#pragma unroll
  for (int o = 1; o < 64; o <<= 1) ssum += __shfl_xor(ssum, o);
  int w = t >> 6;
  if ((t & 63) == 0) red[w] = ssum;
  __syncthreads();
  float mu = (red[0] + red[1] + red[2] + red[3]) * (1.0f / 768.0f);
  float d0 = e0 - mu, d1 = e1 - mu, d2 = e2 - mu;
  float sq = d0 * d0 + d1 * d1 + d2 * d2;
#pragma unroll
  for (int o = 1; o < 64; o <<= 1) sq += __shfl_xor(sq, o);
  __syncthreads();
  if ((t & 63) == 0) red[4 + w] = sq;
  __syncthreads();
  float var = (red[4] + red[5] + red[6] + red[7]) * (1.0f / 768.0f);
  float rstd = 1.0f / sqrtf(var + 1e-7f);
  xr[t] = d0 * rstd * sc[t] + bi[t];
  xr[t + 256] = d1 * rstd * sc[t + 256] + bi[t + 256];
  xr[t + 512] = d2 * rstd * sc[t + 512] + bi[t + 512];
}

extern "C" void kernel_launch(void* const* d_in, const int* in_sizes, int n_in,
                              void* d_out, int out_size, void* d_ws,
                              size_t ws_size, hipStream_t stream) {
  (void)in_sizes; (void)n_in; (void)out_size; (void)ws_size;
  const float* hidden = (const float*)d_in[0];
  const float* relpos = (const float*)d_in[1];
  const float* Wq = (const float*)d_in[2];
  const float* bq = (const float*)d_in[3];
  const float* Wk = (const float*)d_in[4];
  const float* bk = (const float*)d_in[5];
  const float* Wv = (const float*)d_in[6];
  const float* bv = (const float*)d_in[7];
  const float* Wo = (const float*)d_in[8];
  const float* bo = (const float*)d_in[9];
  const float* lns = (const float*)d_in[10];
  const float* lnb = (const float*)d_in[11];
  float* out = (float*)d_out;

  // Workspace (ushort units), total 206,438,400 B (<= proven 207,618,048 B):
  // q | k | vt | ctx | posq | posk | WqkvT (WoT aliases WqkvT)
  unsigned short* ws = (unsigned short*)d_ws;
  const size_t QE = (size_t)48 * SEQ * HDIM;  // 25,165,824
  unsigned short* qws = ws;
  unsigned short* kws = qws + QE;
  unsigned short* vt = kws + QE;
  unsigned short* ctx = vt + QE;
  unsigned short* posq = ctx + QE;
  unsigned short* posk = posq + (size_t)NHEADS * PBUCK * HDIM;
  unsigned short* WqkvT = posk + (size_t)NHEADS * PBUCK * HDIM;
  unsigned short* WoT = WqkvT;  // alias: WqkvT dead before conv of Wo

  static bool attrib_set = false;
  if (!attrib_set) {
    hipFuncSetAttribute((const void*)attn_kernel,
                        hipFuncAttributeMaxDynamicSharedMemorySize, SMEM_BYTES);
    attrib_set = true;
  }

  conv_wt<<<dim3(12, 12, 3), 256, 0, stream>>>(Wq, Wk, Wv, WqkvT);
  pos_gemm<<<dim3(8, 24), 256, 0, stream>>>(relpos, Wq, Wk, bq, bk, posq, posk);
  qkv_mfma<<<dim3(18, 256), 256, 0, stream>>>(hidden, WqkvT, bq, bk, bv, qws,
                                              kws, vt);
  conv_wt<<<dim3(12, 12, 1), 256, 0, stream>>>(Wo, Wo, Wo, WoT);
  attn_kernel<<<3072, 512, SMEM_BYTES, stream>>>(qws, kws, vt, posq, posk, ctx);
  out_mfma<<<dim3(6, 256), 256, 0, stream>>>(ctx, WoT, bo, hidden, out);
  ln_kernel<<<32768, 256, 0, stream>>>(out, lns, lnb);
}